// Round 8
// baseline (428.346 us; speedup 1.0000x reference)
//
#include <hip/hip_runtime.h>

typedef __attribute__((ext_vector_type(4))) float f32x4;
typedef __attribute__((ext_vector_type(16))) float f32x16;
typedef __attribute__((ext_vector_type(8))) _Float16 half8;
typedef __attribute__((ext_vector_type(4))) _Float16 half4;

__device__ __forceinline__ float fast_tanh(float x) {
  float e = __expf(2.f * x);
  return 1.f - 2.f / (e + 1.f);
}
__device__ __forceinline__ float fast_sigmoid(float x) {
  return 1.f / (1.f + __expf(-x));
}

__device__ __forceinline__ void gl_lds16(const _Float16* g, _Float16* l) {
  __builtin_amdgcn_global_load_lds(
      (const __attribute__((address_space(1))) void*)g,
      (__attribute__((address_space(3))) void*)l, 16, 0, 0);
}

// ---------------------------------------------------------------------------
// C[M,N] = A[M,K] @ B[N,K]^T, fp16 (hi/lo split-3 optional), f32 accum.
// 128x128 tile, 4 waves, BK=32, double-buffered LDS, counted-vmcnt pipeline
// (round-5 measured-best loop). MFMA = 32x32x16 (2x2 tiles/wave): 24 MFMA
// x 8.07cyc = 194cyc/step split-3 vs 48x4.85 = 233 for 16x16x32 (-17%).
// LDS XOR-granule swizzle on both sides; 32x32 frag reads stay bank-balanced
// (8 lanes per 4-bank group = 8-cyc floor).
// blockIdx: x = N-tile (fastest), y = M-tile, z = K-split (SWAPXY swaps x/y).
// ---------------------------------------------------------------------------
template<int SPLIT, int OUT16, int NGUARD, int SWAPXY>
__global__ __launch_bounds__(256) void gemm16(
    const _Float16* __restrict__ Ahp, const _Float16* __restrict__ Alp, int lda,
    const _Float16* __restrict__ Bhp, const _Float16* __restrict__ Blp, int ldb,
    void* __restrict__ Cp, int ldc, long czstride,
    int N, int Kc)
{
  __shared__ _Float16 sAh[2][128 * 32];
  __shared__ _Float16 sBh[2][128 * 32];
  __shared__ _Float16 sAl[SPLIT == 3 ? 2 : 1][SPLIT == 3 ? 128 * 32 : 8];
  __shared__ _Float16 sBl[SPLIT == 3 ? 2 : 1][SPLIT == 3 ? 128 * 32 : 8];

  const int tid = threadIdx.x, lane = tid & 63, wid = tid >> 6;
  const int wm = wid >> 1, wn = wid & 1;
  const int l32 = lane & 31, h32 = lane >> 5;
  const int sr = lane >> 2;
  const int scol = ((lane & 3) ^ ((lane >> 3) & 3)) * 8;   // swizzled src col
  // fragment read offsets: granule (ks*2 + h32) XOR row-swizzle ((l32>>1)&3)
  const int rswz = (l32 >> 1) & 3;
  int ko[2];
  ko[0] = ((h32)     ^ rswz) * 8;
  ko[1] = ((2 + h32) ^ rswz) * 8;

  const int  kt0   = blockIdx.z * Kc;
  const long abase = (long)(SWAPXY ? blockIdx.x : blockIdx.y) * 128;
  const long bbase = (long)(SWAPXY ? blockIdx.y : blockIdx.x) * 128;

  const int r0 = wid * 32 + sr;
  const int r1 = wid * 32 + 16 + sr;
  long br0 = bbase + r0, br1 = bbase + r1;
  if (NGUARD) {
    if (br0 > N - 1) br0 = N - 1;
    if (br1 > N - 1) br1 = N - 1;
  }

  const _Float16* ga0 = Ahp + (abase + r0) * (long)lda + kt0 + scol;
  const _Float16* ga1 = Ahp + (abase + r1) * (long)lda + kt0 + scol;
  const _Float16* gb0 = Bhp + br0 * (long)ldb + kt0 + scol;
  const _Float16* gb1 = Bhp + br1 * (long)ldb + kt0 + scol;
  const _Float16* la0 = SPLIT == 3 ? Alp + (abase + r0) * (long)lda + kt0 + scol : nullptr;
  const _Float16* la1 = SPLIT == 3 ? Alp + (abase + r1) * (long)lda + kt0 + scol : nullptr;
  const _Float16* lb0 = SPLIT == 3 ? Blp + br0 * (long)ldb + kt0 + scol : nullptr;
  const _Float16* lb1 = SPLIT == 3 ? Blp + br1 * (long)ldb + kt0 + scol : nullptr;

  const int e0 = (wid * 32) * 32;        // wave-uniform LDS elem base, chunk 0
  const int e1 = (wid * 32 + 16) * 32;   // chunk 1

  f32x16 acc[2][2];
#pragma unroll
  for (int i = 0; i < 2; i++)
#pragma unroll
    for (int j = 0; j < 2; j++)
#pragma unroll
      for (int r = 0; r < 16; r++) acc[i][j][r] = 0.f;

  auto STAGE = [&](int buf, int kk) {
    gl_lds16(ga0 + kk, &sAh[buf][e0]);
    gl_lds16(ga1 + kk, &sAh[buf][e1]);
    gl_lds16(gb0 + kk, &sBh[buf][e0]);
    gl_lds16(gb1 + kk, &sBh[buf][e1]);
    if (SPLIT == 3) {
      gl_lds16(la0 + kk, &sAl[buf][e0]);
      gl_lds16(la1 + kk, &sAl[buf][e1]);
      gl_lds16(lb0 + kk, &sBl[buf][e0]);
      gl_lds16(lb1 + kk, &sBl[buf][e1]);
    }
  };

  STAGE(0, 0);

  const int nst = Kc >> 5;
  for (int t = 0; t < nst; t++) {
    const int buf = t & 1;
    if (t + 1 < nst) {
      STAGE(buf ^ 1, (t + 1) * 32);
      // wait only for PREV step's loads (the just-issued stay in flight)
      if (SPLIT == 3) asm volatile("s_waitcnt vmcnt(8)" ::: "memory");
      else            asm volatile("s_waitcnt vmcnt(4)" ::: "memory");
    } else {
      asm volatile("s_waitcnt vmcnt(0)" ::: "memory");
    }
    __builtin_amdgcn_sched_barrier(0);
    __builtin_amdgcn_s_barrier();          // all waves' buf loads visible
    __builtin_amdgcn_sched_barrier(0);

    half8 a0[2][2], b0[2][2];
#pragma unroll
    for (int mt = 0; mt < 2; mt++)
#pragma unroll
      for (int ks = 0; ks < 2; ks++)
        a0[mt][ks] = *(const half8*)&sAh[buf][(wm * 64 + mt * 32 + l32) * 32 + ko[ks]];
#pragma unroll
    for (int nt = 0; nt < 2; nt++)
#pragma unroll
      for (int ks = 0; ks < 2; ks++)
        b0[nt][ks] = *(const half8*)&sBh[buf][(wn * 64 + nt * 32 + l32) * 32 + ko[ks]];
#pragma unroll
    for (int mt = 0; mt < 2; mt++)
#pragma unroll
      for (int nt = 0; nt < 2; nt++)
#pragma unroll
        for (int ks = 0; ks < 2; ks++)
          acc[mt][nt] = __builtin_amdgcn_mfma_f32_32x32x16_f16(
              a0[mt][ks], b0[nt][ks], acc[mt][nt], 0, 0, 0);
    if (SPLIT == 3) {
      half8 al_[2][2], bl_[2][2];
#pragma unroll
      for (int mt = 0; mt < 2; mt++)
#pragma unroll
        for (int ks = 0; ks < 2; ks++)
          al_[mt][ks] = *(const half8*)&sAl[buf][(wm * 64 + mt * 32 + l32) * 32 + ko[ks]];
#pragma unroll
      for (int nt = 0; nt < 2; nt++)
#pragma unroll
        for (int ks = 0; ks < 2; ks++)
          bl_[nt][ks] = *(const half8*)&sBl[buf][(wn * 64 + nt * 32 + l32) * 32 + ko[ks]];
#pragma unroll
      for (int mt = 0; mt < 2; mt++)
#pragma unroll
        for (int nt = 0; nt < 2; nt++)
#pragma unroll
          for (int ks = 0; ks < 2; ks++) {
            acc[mt][nt] = __builtin_amdgcn_mfma_f32_32x32x16_f16(
                al_[mt][ks], b0[nt][ks], acc[mt][nt], 0, 0, 0);
            acc[mt][nt] = __builtin_amdgcn_mfma_f32_32x32x16_f16(
                a0[mt][ks], bl_[nt][ks], acc[mt][nt], 0, 0, 0);
          }
    }
    __builtin_amdgcn_sched_barrier(0);
    __builtin_amdgcn_s_barrier();          // WAR guard: reads of buf done
    __builtin_amdgcn_sched_barrier(0);
  }

  const long czoff = (long)blockIdx.z * czstride;
#pragma unroll
  for (int mt = 0; mt < 2; mt++)
#pragma unroll
    for (int nt = 0; nt < 2; nt++) {
      const long rowb = abase + wm * 64 + mt * 32;
      const long col  = bbase + wn * 64 + nt * 32 + l32;
      if (!NGUARD || col < N) {
#pragma unroll
        for (int r = 0; r < 16; r++) {
          const long row = rowb + (r & 3) + 8 * (r >> 2) + 4 * h32;
          const long idx = row * (long)ldc + col + czoff;
          if (OUT16) ((_Float16*)Cp)[idx] = (_Float16)acc[mt][nt][r];
          else       ((float*)Cp)[idx] = acc[mt][nt][r];
        }
      }
    }
}

// ---------------------------------------------------------------------------
// prep: all weight converts + X1 hi/lo pack in ONE kernel (block-range dispatch)
__global__ __launch_bounds__(256) void prep_kernel(
    const float* __restrict__ WihA, const float* __restrict__ WhhA,
    const float* __restrict__ WihL, const float* __restrict__ WhhL,
    const float* __restrict__ Wh1, const float* __restrict__ Wh2,
    const float* __restrict__ Wvf, const float* __restrict__ Wpvf,
    const float* __restrict__ xt, const float* __restrict__ fc,
    const float* __restrict__ sh,
    _Float16* __restrict__ WcAh, _Float16* __restrict__ WcAl,
    _Float16* __restrict__ WcLh, _Float16* __restrict__ W12h,
    _Float16* __restrict__ Wvfh, _Float16* __restrict__ Wvfl,
    _Float16* __restrict__ Wpvfh,
    _Float16* __restrict__ X1h, _Float16* __restrict__ X1l)
{
  int bi = blockIdx.x, t = threadIdx.x;
  if (bi < 16384) {                       // Wc_att [4096][4096] hi+lo
    long e = ((long)bi * 256 + t) * 4;
    int row = (int)(e >> 12), col = (int)(e & 4095);
    const float* src = (col < 3072) ? WihA + (long)row * 3072 + col
                                    : WhhA + (long)row * 1024 + (col - 3072);
    f32x4 v = *(const f32x4*)src;
    half4 h, l;
#pragma unroll
    for (int j = 0; j < 4; j++) { h[j] = (_Float16)v[j]; l[j] = (_Float16)(v[j] - (float)h[j]); }
    *(half4*)&WcAh[e] = h;
    *(half4*)&WcAl[e] = l;
  } else if (bi < 32768) {                // Wc_lang [4096][4096] hi only
    long e = ((long)(bi - 16384) * 256 + t) * 4;
    int row = (int)(e >> 12), col = (int)(e & 4095);
    const float* src = (col < 3072) ? WihL + (long)row * 3072 + col
                                    : WhhL + (long)row * 1024 + (col - 3072);
    f32x4 v = *(const f32x4*)src;
    half4 h;
#pragma unroll
    for (int j = 0; j < 4; j++) h[j] = (_Float16)v[j];
    *(half4*)&WcLh[e] = h;
  } else if (bi < 33792) {                // Whh12 [1024][1024]
    long e = ((long)(bi - 32768) * 256 + t) * 4;
    int row = (int)(e >> 10), col = (int)(e & 1023);
    const float* src = (row < 512) ? Wh1 + (long)row * 1024 + col
                                   : Wh2 + (long)(row - 512) * 1024 + col;
    f32x4 v = *(const f32x4*)src;
    half4 h;
#pragma unroll
    for (int j = 0; j < 4; j++) h[j] = (_Float16)v[j];
    *(half4*)&W12h[e] = h;
  } else if (bi < 34184) {                // Wvf [196][2048] hi+lo
    long e = ((long)(bi - 33792) * 256 + t) * 4;
    f32x4 v = *(const f32x4*)(Wvf + e);
    half4 h, l;
#pragma unroll
    for (int j = 0; j < 4; j++) { h[j] = (_Float16)v[j]; l[j] = (_Float16)(v[j] - (float)h[j]); }
    *(half4*)&Wvfh[e] = h;
    *(half4*)&Wvfl[e] = l;
  } else if (bi < 34696) {                // Wpvf [512][1024]
    long e = ((long)(bi - 34184) * 256 + t) * 4;
    f32x4 v = *(const f32x4*)(Wpvf + e);
    half4 h;
#pragma unroll
    for (int j = 0; j < 4; j++) h[j] = (_Float16)v[j];
    *(half4*)&Wpvfh[e] = h;
  } else {                                // X1 pack hi/lo
    int i = (bi - 34696) * 256 + t;       // [0, 512*1024)
    int b = i >> 10, rr = i & 1023;
    long base = (long)b * 4096;
    float v[4];
    v[0] = sh[524288 + i];   // prev_h = state_h[1]
    v[1] = fc[i];
    v[2] = xt[i];
    v[3] = sh[i];            // state_h[0] (hidden)
#pragma unroll
    for (int j = 0; j < 4; j++) {
      _Float16 h = (_Float16)v[j];
      X1h[base + j * 1024 + rr] = h;
      X1l[base + j * 1024 + rr] = (_Float16)(v[j] - (float)h);
    }
  }
}

// LSTM activation; sums NP K-split partials (f32 or fp16 per H16).
// ATT variant also fills hatt_h, conc hi/lo slot, and X2h slots 1024/3072.
template<int NP, bool H16, bool ATT>
__global__ __launch_bounds__(256) void lstm_act_kernel(
    const void* __restrict__ gp, const float* __restrict__ bih,
    const float* __restrict__ bhh, const float* __restrict__ cin,
    float* __restrict__ hOut, float* __restrict__ cOut,
    _Float16* __restrict__ hatt_h, _Float16* __restrict__ conch,
    _Float16* __restrict__ concl, _Float16* __restrict__ x2h,
    const float* __restrict__ sh, float* __restrict__ hOut2)
{
  const long S = 2097152;   // 512*4096
  int i = blockIdx.x * 256 + threadIdx.x;   // [0, 512*1024)
  int b = i >> 10, rr = i & 1023;
  long gb = (long)b * 4096;
  float g4[4];
#pragma unroll
  for (int q = 0; q < 4; q++) {
    float s = 0.f;
#pragma unroll
    for (int z = 0; z < NP; z++) {
      long off = (long)z * S + gb + q * 1024 + rr;
      s += H16 ? (float)((const _Float16*)gp)[off] : ((const float*)gp)[off];
    }
    g4[q] = s + bih[q * 1024 + rr] + bhh[q * 1024 + rr];
  }
  float c  = cin[i];
  float c2 = fast_sigmoid(g4[1]) * c + fast_sigmoid(g4[0]) * fast_tanh(g4[2]);
  float h2 = fast_sigmoid(g4[3]) * fast_tanh(c2);
  hOut[i] = h2;
  cOut[i] = c2;
  if (hOut2) hOut2[i] = h2;
  if (ATT) {
    _Float16 hh = (_Float16)h2;
    hatt_h[i] = hh;
    conch[(long)b * 2048 + 1024 + rr] = hh;
    concl[(long)b * 2048 + 1024 + rr] = (_Float16)(h2 - (float)hh);
    x2h[(long)b * 4096 + 1024 + rr] = hh;
    x2h[(long)b * 4096 + 3072 + rr] = (_Float16)sh[524288 + i];
  }
}

// attention-1 scores (one wave per (b,s) row); sums 4 atth partials inline
__global__ __launch_bounds__(256) void score1_kernel(
    const float* __restrict__ pf, const float* __restrict__ atthp,
    const float* __restrict__ bh,
    const float* __restrict__ walpha, const float* __restrict__ balpha,
    float* __restrict__ out, int nrows)
{
  int gw = blockIdx.x * 4 + (threadIdx.x >> 6);
  int lane = threadIdx.x & 63;
  if (gw >= nrows) return;
  int b = gw / 196;
  const float* p  = pf + (long)gw * 512 + lane * 8;
  const float* bp = bh + lane * 8;
  const float* wp = walpha + lane * 8;
  f32x4 av[2] = {(f32x4){0.f,0.f,0.f,0.f}, (f32x4){0.f,0.f,0.f,0.f}};
#pragma unroll
  for (int z = 0; z < 4; z++) {
    const float* ap = atthp + (long)z * 524288 + (long)b * 1024 + lane * 8;
    av[0] += *(const f32x4*)(ap);
    av[1] += *(const f32x4*)(ap + 4);
  }
  float acc = 0.f;
#pragma unroll
  for (int u = 0; u < 2; u++) {
    f32x4 pv = *(const f32x4*)(p + u * 4);
    f32x4 bv = *(const f32x4*)(bp + u * 4);
    f32x4 wv = *(const f32x4*)(wp + u * 4);
#pragma unroll
    for (int j = 0; j < 4; j++)
      acc += fast_tanh(pv[j] + av[u][j] + bv[j]) * wv[j];
  }
#pragma unroll
  for (int off = 32; off; off >>= 1) acc += __shfl_xor(acc, off);
  if (lane == 0) out[gw] = acc + balpha[0];
}

__global__ __launch_bounds__(256) void attsum1_kernel(
    const float* __restrict__ scores, const float* __restrict__ feats,
    _Float16* __restrict__ conch, _Float16* __restrict__ concl, _Float16* __restrict__ x2h)
{
  __shared__ float w[256];
  int b = blockIdx.x, t = threadIdx.x;
  float s0 = (t < 196) ? scores[b * 196 + t] : -3.0e38f;
  w[t] = s0;
  __syncthreads();
  float mx = -3.0e38f;
  for (int i = 0; i < 196; i++) mx = fmaxf(mx, w[i]);
  float sum = 0.f;
  for (int i = 0; i < 196; i++) sum += __expf(w[i] - mx);
  float inv = 1.f / sum;
  __syncthreads();
  if (t < 196) w[t] = __expf(s0 - mx) * inv;
  __syncthreads();
  f32x4 acc = (f32x4){0.f, 0.f, 0.f, 0.f};
  const float* fb = feats + (long)b * 200704 + t * 4;
  for (int s0i = 0; s0i < 192; s0i += 8) {
    f32x4 v[8];
#pragma unroll
    for (int u = 0; u < 8; u++) v[u] = *(const f32x4*)(fb + (long)(s0i + u) * 1024);
#pragma unroll
    for (int u = 0; u < 8; u++) {
      float ws = w[s0i + u];
#pragma unroll
      for (int j = 0; j < 4; j++) acc[j] += ws * v[u][j];
    }
  }
#pragma unroll
  for (int u = 192; u < 196; u++) {
    float ws = w[u];
    f32x4 v = *(const f32x4*)(fb + (long)u * 1024);
#pragma unroll
    for (int j = 0; j < 4; j++) acc[j] += ws * v[j];
  }
  half4 h, l;
#pragma unroll
  for (int j = 0; j < 4; j++) { h[j] = (_Float16)acc[j]; l[j] = (_Float16)(acc[j] - (float)h[j]); }
  *(half4*)&conch[(long)b * 2048 + t * 4] = h;
  *(half4*)&concl[(long)b * 2048 + t * 4] = l;
  *(half4*)&x2h[(long)b * 4096 + 2048 + t * 4] = h;
}

// merged attention-2: scores + softmax + weighted sum (atth2 from 4 partials)
__global__ __launch_bounds__(256) void vfatt_kernel(
    const _Float16* __restrict__ pvf16, const float* __restrict__ atthp,
    const float* __restrict__ bh2att2, const float* __restrict__ b_pvf,
    const float* __restrict__ walpha2, const float* __restrict__ balpha2,
    const _Float16* __restrict__ arr1h, _Float16* __restrict__ x2h)
{
  __shared__ float w[40];
  int b = blockIdx.x, tid = threadIdx.x;
  int lane = tid & 63, wv = tid >> 6;

  float add[8], wal[8];
#pragma unroll
  for (int u = 0; u < 8; u++) {
    int a = lane * 8 + u;
    add[u] = bh2att2[a] + b_pvf[a];
    wal[u] = walpha2[a];
  }
#pragma unroll
  for (int z = 0; z < 4; z++) {
    const float* ap = atthp + (long)z * 524288 + (long)b * 1024 + 512 + lane * 8;
#pragma unroll
    for (int u = 0; u < 8; u++) add[u] += ap[u];
  }
  for (int j = wv; j < 36; j += 4) {
    half8 hv = *(const half8*)&pvf16[((long)b * 36 + j) * 512 + lane * 8];
    float acc = 0.f;
#pragma unroll
    for (int u = 0; u < 8; u++)
      acc += fast_tanh((float)hv[u] + add[u]) * wal[u];
#pragma unroll
    for (int off = 32; off; off >>= 1) acc += __shfl_xor(acc, off);
    if (lane == 0) w[j] = acc + balpha2[0];
  }
  __syncthreads();
  float mx = -3.0e38f;
  for (int i = 0; i < 36; i++) mx = fmaxf(mx, w[i]);
  float sum = 0.f;
  for (int i = 0; i < 36; i++) sum += __expf(w[i] - mx);
  float inv = 1.f / sum;
  __syncthreads();
  if (tid < 36) w[tid] = __expf(w[tid] - mx) * inv;
  __syncthreads();
  f32x4 acc = (f32x4){0.f, 0.f, 0.f, 0.f};
  const _Float16* fb = arr1h + (long)b * 36 * 1024 + tid * 4;
#pragma unroll 4
  for (int s = 0; s < 36; s++) {
    float ws = w[s];
    half4 v = *(const half4*)(fb + (long)s * 1024);
#pragma unroll
    for (int j = 0; j < 4; j++) acc[j] += ws * (float)v[j];
  }
  half4 h;
#pragma unroll
  for (int j = 0; j < 4; j++) h[j] = (_Float16)acc[j];
  *(half4*)&x2h[(long)b * 4096 + tid * 4] = h;
}

// one wave per b: top-36 of (sum_z vfhap[z,b,s]) + b_vf[s]  (index set only)
template<int NP>
__global__ __launch_bounds__(64) void topk_kernel(
    const float* __restrict__ vfp, const float* __restrict__ b_vf, int* __restrict__ ix)
{
  int b = blockIdx.x;
  int lane = threadIdx.x;
  float v[4];
#pragma unroll
  for (int j = 0; j < 4; j++) {
    int s = lane + 64 * j;
    float sum = -3.0e38f;
    if (s < 196) {
      sum = b_vf[s];
#pragma unroll
      for (int z = 0; z < NP; z++) sum += vfp[(long)z * 100352 + b * 196 + s];
    }
    v[j] = sum;
  }
  for (int it = 0; it < 36; it++) {
    float bv = -3.0e38f; int bs = 1 << 20;
#pragma unroll
    for (int j = 0; j < 4; j++) {
      int s = lane + 64 * j;
      if (v[j] > bv) { bv = v[j]; bs = s; }
    }
#pragma unroll
    for (int off = 32; off; off >>= 1) {
      float ov = __shfl_xor(bv, off);
      int   os = __shfl_xor(bs, off);
      if (ov > bv || (ov == bv && os < bs)) { bv = ov; bs = os; }
    }
    if ((bs & 63) == lane) v[bs >> 6] = -3.0e38f;
    if (lane == 0) ix[b * 36 + it] = bs;
  }
}

__global__ __launch_bounds__(256) void gather_conv_kernel(
    const float* __restrict__ feats, const int* __restrict__ ix, _Float16* __restrict__ dst)
{
  int bj = blockIdx.x;
  int b = bj / 36;
  int s = ix[bj];
  int t = threadIdx.x;
  f32x4 v = *(const f32x4*)(feats + ((long)b * 196 + s) * 1024 + t * 4);
  half4 h;
#pragma unroll
  for (int j = 0; j < 4; j++) h[j] = (_Float16)v[j];
  *(half4*)&dst[(long)bj * 1024 + t * 4] = h;
}

// ---------------------------------------------------------------------------
extern "C" void kernel_launch(void* const* d_in, const int* in_sizes, int n_in,
                              void* d_out, int out_size, void* d_ws, size_t ws_size,
                              hipStream_t stream) {
  const float* xt        = (const float*)d_in[0];
  const float* fc_feats  = (const float*)d_in[1];
  const float* att_feats = (const float*)d_in[2];
  const float* p_att     = (const float*)d_in[3];
  const float* state_h   = (const float*)d_in[4];
  const float* state_c   = (const float*)d_in[5];
  const float* b_ih_att  = (const float*)d_in[7];
  const float* b_hh_att  = (const float*)d_in[9];
  const float* b_ih_lang = (const float*)d_in[11];
  const float* b_hh_lang = (const float*)d_in[13];
  const float* bh2att1   = (const float*)d_in[15];
  const float* Walpha1   = (const float*)d_in[16];
  const float* balpha1   = (const float*)d_in[17];
  const float* bh2att2   = (const float*)d_in[19];
  const float* Walpha2   = (const float*)d_in[20];
  const float* balpha2   = (const float*)d_in[21];
  const float* b_vf      = (const float*)d_in[23];
  const float* b_pvf     = (const float*)d_in[25];

  float* out = (float*)d_out;
  float* W = (float*)d_ws;   // pool, f32-unit offsets; flat layout

  _Float16* WcAh   = (_Float16*)(W + 0);         // [4096][4096] fp16 hi
  _Float16* WcAl   = (_Float16*)(W + 8388608);   // [4096][4096] fp16 lo
  _Float16* WcLh   = (_Float16*)(W + 16777216);  // [4096][4096] fp16 (lang)
  _Float16* X1h    = (_Float16*)(W + 25165824);  // [512][4096]
  _Float16* X1l    = (_Float16*)(W + 26214400);  // [512][4096]
  float*    g1p    = W + 27262976;               // [4][512][4096] f32
  _Float16* hatt_h = (_Float16*)(W + 35651584);  // [512][1024]
  _Float16* W12h   = (_Float16*)(W + 35913728);  // [1024][1024]
  _Float16* Wvfh   = (_Float16*)(W + 36438016);  // [196][2048]
  _Float16* Wvfl   = (_Float16*)(W + 36638720);  // [196][2048]
  _Float16* Wpvfh  = (_Float16*)(W + 36839424);  // [512][1024]
  float*    atthp  = W + 37101568;               // [4][512][1024] f32
  _Float16* conch  = (_Float16*)(W + 39198720);  // [512][2048]
  _Float16* concl  = (_Float16*)(W + 39723008);  // [512][2048]
  _Float16* X2h    = (_Float16*)(W + 40247296);  // [512][4096]
  float*    scores1= W + 41295872;               // [512*196]
  float*    vfhap  = W + 41396224;               // [16][512][196] f32
  int*      vfix   = (int*)(W + 43001856);       // [512*36]
  _Float16* arr1h  = (_Float16*)(W + 43020288);  // [18432][1024]
  _Float16* pvf16  = (_Float16*)(W + 52457472);  // [18432][512]
  _Float16* g2ph   = (_Float16*)(W + 57176064);  // [4][512][4096] fp16

  float* out_h0 = out + 524288;
  float* out_h1 = out + 2 * 524288;
  float* out_c0 = out + 3 * 524288;
  float* out_c1 = out + 4 * 524288;

  // 1. prep: all weight converts + X1 hi/lo pack (one kernel)
  prep_kernel<<<36744, 256, 0, stream>>>(
      (const float*)d_in[6], (const float*)d_in[8],
      (const float*)d_in[10], (const float*)d_in[12],
      (const float*)d_in[14], (const float*)d_in[18],
      (const float*)d_in[22], (const float*)d_in[24],
      xt, fc_feats, state_h,
      WcAh, WcAl, WcLh, W12h, Wvfh, Wvfl, Wpvfh, X1h, X1l);

  // 2. att-LSTM gates: split-3, z=4 (512 blocks = 2/CU), counted-vmcnt pipeline
  gemm16<3, 0, 0, 0><<<dim3(32, 4, 4), 256, 0, stream>>>(
      X1h, X1l, 4096, WcAh, WcAl, 4096, g1p, 4096, 2097152, 4096, 1024);

  // 3. att-LSTM activation (sums 4 f32 partials; fills conc/X2h slots)
  lstm_act_kernel<4, false, true><<<2048, 256, 0, stream>>>(
      g1p, b_ih_att, b_hh_att, state_c, out_h0, out_c0,
      hatt_h, conch, concl, X2h, state_h, nullptr);

  // 4. fused atth1|atth2 projection, z=4 (partials consumed by score1/vfatt)
  gemm16<1, 0, 0, 0><<<dim3(8, 4, 4), 256, 0, stream>>>(
      hatt_h, nullptr, 1024, W12h, nullptr, 1024, atthp, 1024, 524288, 1024, 256);

  // 5. attention-1 scores (sums atth partials inline)
  score1_kernel<<<25088, 256, 0, stream>>>(
      p_att, atthp, bh2att1, Walpha1, balpha1, scores1, 100352);

  // 6. attention-1 softmax + weighted sum
  attsum1_kernel<<<512, 256, 0, stream>>>(scores1, att_feats, conch, concl, X2h);

  // 7. vf logits, split-3, z=16 (128 blocks; partials summed in topk)
  gemm16<3, 0, 1, 0><<<dim3(2, 4, 16), 256, 0, stream>>>(
      conch, concl, 2048, Wvfh, Wvfl, 2048, vfhap, 196, 100352, 196, 128);

  // 8. top-36
  topk_kernel<16><<<512, 64, 0, stream>>>(vfhap, b_vf, vfix);

  // 9. gather + fp16 convert
  gather_conv_kernel<<<18432, 256, 0, stream>>>(att_feats, vfix, arr1h);

  // 10. p_vf_feats (fp16 out); SWAPXY: same-M blocks stride 144 (=0 mod 8)
  gemm16<1, 1, 0, 1><<<dim3(144, 4, 1), 256, 0, stream>>>(
      arr1h, nullptr, 1024, Wpvfh, nullptr, 1024, pvf16, 512, 0, 512, 1024);

  // 11. attention-2 merged: scores + softmax + weighted sum -> X2h[:,0:1024]
  vfatt_kernel<<<512, 256, 0, stream>>>(
      pvf16, atthp, bh2att2, b_pvf, Walpha2, balpha2, arr1h, X2h);

  // 12. lang-LSTM gates: plain fp16, z=4, fp16 partials
  gemm16<1, 1, 0, 0><<<dim3(32, 4, 4), 256, 0, stream>>>(
      X2h, nullptr, 4096, WcLh, nullptr, 4096, g2ph, 4096, 2097152, 4096, 1024);

  // 13. lang-LSTM activation -> output (sums 4 fp16 partials)
  lstm_act_kernel<4, true, false><<<2048, 256, 0, stream>>>(
      g2ph, b_ih_lang, b_hh_lang, state_c + 524288, out, out_c1,
      nullptr, nullptr, nullptr, nullptr, nullptr, out_h1);
}

// Round 9
// 414.137 us; speedup vs baseline: 1.0343x; 1.0343x over previous
//
#include <hip/hip_runtime.h>

typedef __attribute__((ext_vector_type(4))) float f32x4;
typedef __attribute__((ext_vector_type(8))) _Float16 half8;
typedef __attribute__((ext_vector_type(4))) _Float16 half4;

__device__ __forceinline__ float fast_tanh(float x) {
  float e = __expf(2.f * x);
  return 1.f - 2.f / (e + 1.f);
}
__device__ __forceinline__ float fast_sigmoid(float x) {
  return 1.f / (1.f + __expf(-x));
}

__device__ __forceinline__ void gl_lds16(const _Float16* g, _Float16* l) {
  __builtin_amdgcn_global_load_lds(
      (const __attribute__((address_space(1))) void*)g,
      (__attribute__((address_space(3))) void*)l, 16, 0, 0);
}

// ---------------------------------------------------------------------------
// ROUND-5 MEASURED-BEST GEMM (do not touch): C[M,N] = A[M,K] @ B[N,K]^T,
// fp16 (hi/lo split-3 optional), f32 accum. 128x128 tile, 4 waves, BK=32,
// double-buffered LDS, counted-vmcnt pipeline, 16x16x32 MFMA.
// ---------------------------------------------------------------------------
template<int SPLIT, int OUT16, int NGUARD, int SWAPXY>
__global__ __launch_bounds__(256) void gemm16(
    const _Float16* __restrict__ Ahp, const _Float16* __restrict__ Alp, int lda,
    const _Float16* __restrict__ Bhp, const _Float16* __restrict__ Blp, int ldb,
    void* __restrict__ Cp, int ldc, long czstride,
    int N, int Kc)
{
  __shared__ _Float16 sAh[2][128 * 32];
  __shared__ _Float16 sBh[2][128 * 32];
  __shared__ _Float16 sAl[SPLIT == 3 ? 2 : 1][SPLIT == 3 ? 128 * 32 : 8];
  __shared__ _Float16 sBl[SPLIT == 3 ? 2 : 1][SPLIT == 3 ? 128 * 32 : 8];

  const int tid = threadIdx.x, lane = tid & 63, wid = tid >> 6;
  const int wm = wid >> 1, wn = wid & 1;
  const int l16 = lane & 15, k8 = lane >> 4;
  const int sr = lane >> 2;
  const int scol = ((lane & 3) ^ ((lane >> 3) & 3)) * 8;   // swizzled src col
  const int koff = ((k8 ^ ((lane >> 1) & 3))) * 8;         // swizzled read off

  const int  kt0   = blockIdx.z * Kc;
  const long abase = (long)(SWAPXY ? blockIdx.x : blockIdx.y) * 128;
  const long bbase = (long)(SWAPXY ? blockIdx.y : blockIdx.x) * 128;

  const int r0 = wid * 32 + sr;
  const int r1 = wid * 32 + 16 + sr;
  long br0 = bbase + r0, br1 = bbase + r1;
  if (NGUARD) {
    if (br0 > N - 1) br0 = N - 1;
    if (br1 > N - 1) br1 = N - 1;
  }

  const _Float16* ga0 = Ahp + (abase + r0) * (long)lda + kt0 + scol;
  const _Float16* ga1 = Ahp + (abase + r1) * (long)lda + kt0 + scol;
  const _Float16* gb0 = Bhp + br0 * (long)ldb + kt0 + scol;
  const _Float16* gb1 = Bhp + br1 * (long)ldb + kt0 + scol;
  const _Float16* la0 = SPLIT == 3 ? Alp + (abase + r0) * (long)lda + kt0 + scol : nullptr;
  const _Float16* la1 = SPLIT == 3 ? Alp + (abase + r1) * (long)lda + kt0 + scol : nullptr;
  const _Float16* lb0 = SPLIT == 3 ? Blp + br0 * (long)ldb + kt0 + scol : nullptr;
  const _Float16* lb1 = SPLIT == 3 ? Blp + br1 * (long)ldb + kt0 + scol : nullptr;

  const int e0 = (wid * 32) * 32;        // wave-uniform LDS elem base, chunk 0
  const int e1 = (wid * 32 + 16) * 32;   // chunk 1

  f32x4 acc[4][4];
#pragma unroll
  for (int i = 0; i < 4; i++)
#pragma unroll
    for (int j = 0; j < 4; j++) acc[i][j] = (f32x4){0.f, 0.f, 0.f, 0.f};

  auto STAGE = [&](int buf, int kk) {
    gl_lds16(ga0 + kk, &sAh[buf][e0]);
    gl_lds16(ga1 + kk, &sAh[buf][e1]);
    gl_lds16(gb0 + kk, &sBh[buf][e0]);
    gl_lds16(gb1 + kk, &sBh[buf][e1]);
    if (SPLIT == 3) {
      gl_lds16(la0 + kk, &sAl[buf][e0]);
      gl_lds16(la1 + kk, &sAl[buf][e1]);
      gl_lds16(lb0 + kk, &sBl[buf][e0]);
      gl_lds16(lb1 + kk, &sBl[buf][e1]);
    }
  };

  STAGE(0, 0);

  const int nst = Kc >> 5;
  for (int t = 0; t < nst; t++) {
    const int buf = t & 1;
    if (t + 1 < nst) {
      STAGE(buf ^ 1, (t + 1) * 32);
      // wait only for PREV step's loads (the just-issued stay in flight)
      if (SPLIT == 3) asm volatile("s_waitcnt vmcnt(8)" ::: "memory");
      else            asm volatile("s_waitcnt vmcnt(4)" ::: "memory");
    } else {
      asm volatile("s_waitcnt vmcnt(0)" ::: "memory");
    }
    __builtin_amdgcn_sched_barrier(0);
    __builtin_amdgcn_s_barrier();          // all waves' buf loads visible
    __builtin_amdgcn_sched_barrier(0);

    half8 ah[4], bh[4];
#pragma unroll
    for (int m = 0; m < 4; m++)
      ah[m] = *(const half8*)&sAh[buf][(wm * 64 + m * 16 + l16) * 32 + koff];
#pragma unroll
    for (int n = 0; n < 4; n++)
      bh[n] = *(const half8*)&sBh[buf][(wn * 64 + n * 16 + l16) * 32 + koff];
#pragma unroll
    for (int m = 0; m < 4; m++)
#pragma unroll
      for (int n = 0; n < 4; n++)
        acc[m][n] = __builtin_amdgcn_mfma_f32_16x16x32_f16(ah[m], bh[n], acc[m][n], 0, 0, 0);
    if (SPLIT == 3) {
      half8 al[4], bl[4];
#pragma unroll
      for (int m = 0; m < 4; m++)
        al[m] = *(const half8*)&sAl[buf][(wm * 64 + m * 16 + l16) * 32 + koff];
#pragma unroll
      for (int n = 0; n < 4; n++)
        bl[n] = *(const half8*)&sBl[buf][(wn * 64 + n * 16 + l16) * 32 + koff];
#pragma unroll
      for (int m = 0; m < 4; m++)
#pragma unroll
        for (int n = 0; n < 4; n++) {
          acc[m][n] = __builtin_amdgcn_mfma_f32_16x16x32_f16(al[m], bh[n], acc[m][n], 0, 0, 0);
          acc[m][n] = __builtin_amdgcn_mfma_f32_16x16x32_f16(ah[m], bl[n], acc[m][n], 0, 0, 0);
        }
    }
    __builtin_amdgcn_sched_barrier(0);
    __builtin_amdgcn_s_barrier();          // WAR guard: reads of buf done
    __builtin_amdgcn_sched_barrier(0);
  }

  const long czoff = (long)blockIdx.z * czstride;
#pragma unroll
  for (int m = 0; m < 4; m++)
#pragma unroll
    for (int n = 0; n < 4; n++) {
      const long row0 = abase + wm * 64 + m * 16 + (lane >> 4) * 4;
      const long col  = bbase + wn * 64 + n * 16 + l16;
      if (!NGUARD || col < N) {
#pragma unroll
        for (int j = 0; j < 4; j++) {
          const long idx = (row0 + j) * (long)ldc + col + czoff;
          if (OUT16) ((_Float16*)Cp)[idx] = (_Float16)acc[m][n][j];
          else       ((float*)Cp)[idx] = acc[m][n][j];
        }
      }
    }
}

// ---------------------------------------------------------------------------
// prep: all weight converts + X1 hi/lo pack in ONE kernel (block-range dispatch)
__global__ __launch_bounds__(256) void prep_kernel(
    const float* __restrict__ WihA, const float* __restrict__ WhhA,
    const float* __restrict__ WihL, const float* __restrict__ WhhL,
    const float* __restrict__ Wh1, const float* __restrict__ Wh2,
    const float* __restrict__ Wvf, const float* __restrict__ Wpvf,
    const float* __restrict__ xt, const float* __restrict__ fc,
    const float* __restrict__ sh,
    _Float16* __restrict__ WcAh, _Float16* __restrict__ WcAl,
    _Float16* __restrict__ WcLh, _Float16* __restrict__ W12h,
    _Float16* __restrict__ Wvfh, _Float16* __restrict__ Wvfl,
    _Float16* __restrict__ Wpvfh,
    _Float16* __restrict__ X1h, _Float16* __restrict__ X1l)
{
  int bi = blockIdx.x, t = threadIdx.x;
  if (bi < 16384) {                       // Wc_att [4096][4096] hi+lo
    long e = ((long)bi * 256 + t) * 4;
    int row = (int)(e >> 12), col = (int)(e & 4095);
    const float* src = (col < 3072) ? WihA + (long)row * 3072 + col
                                    : WhhA + (long)row * 1024 + (col - 3072);
    f32x4 v = *(const f32x4*)src;
    half4 h, l;
#pragma unroll
    for (int j = 0; j < 4; j++) { h[j] = (_Float16)v[j]; l[j] = (_Float16)(v[j] - (float)h[j]); }
    *(half4*)&WcAh[e] = h;
    *(half4*)&WcAl[e] = l;
  } else if (bi < 32768) {                // Wc_lang [4096][4096] hi only
    long e = ((long)(bi - 16384) * 256 + t) * 4;
    int row = (int)(e >> 12), col = (int)(e & 4095);
    const float* src = (col < 3072) ? WihL + (long)row * 3072 + col
                                    : WhhL + (long)row * 1024 + (col - 3072);
    f32x4 v = *(const f32x4*)src;
    half4 h;
#pragma unroll
    for (int j = 0; j < 4; j++) h[j] = (_Float16)v[j];
    *(half4*)&WcLh[e] = h;
  } else if (bi < 33792) {                // Whh12 [1024][1024]
    long e = ((long)(bi - 32768) * 256 + t) * 4;
    int row = (int)(e >> 10), col = (int)(e & 1023);
    const float* src = (row < 512) ? Wh1 + (long)row * 1024 + col
                                   : Wh2 + (long)(row - 512) * 1024 + col;
    f32x4 v = *(const f32x4*)src;
    half4 h;
#pragma unroll
    for (int j = 0; j < 4; j++) h[j] = (_Float16)v[j];
    *(half4*)&W12h[e] = h;
  } else if (bi < 34184) {                // Wvf [196][2048] hi+lo
    long e = ((long)(bi - 33792) * 256 + t) * 4;
    f32x4 v = *(const f32x4*)(Wvf + e);
    half4 h, l;
#pragma unroll
    for (int j = 0; j < 4; j++) { h[j] = (_Float16)v[j]; l[j] = (_Float16)(v[j] - (float)h[j]); }
    *(half4*)&Wvfh[e] = h;
    *(half4*)&Wvfl[e] = l;
  } else if (bi < 34696) {                // Wpvf [512][1024]
    long e = ((long)(bi - 34184) * 256 + t) * 4;
    f32x4 v = *(const f32x4*)(Wpvf + e);
    half4 h;
#pragma unroll
    for (int j = 0; j < 4; j++) h[j] = (_Float16)v[j];
    *(half4*)&Wpvfh[e] = h;
  } else {                                // X1 pack hi/lo
    int i = (bi - 34696) * 256 + t;       // [0, 512*1024)
    int b = i >> 10, rr = i & 1023;
    long base = (long)b * 4096;
    float v[4];
    v[0] = sh[524288 + i];   // prev_h = state_h[1]
    v[1] = fc[i];
    v[2] = xt[i];
    v[3] = sh[i];            // state_h[0] (hidden)
#pragma unroll
    for (int j = 0; j < 4; j++) {
      _Float16 h = (_Float16)v[j];
      X1h[base + j * 1024 + rr] = h;
      X1l[base + j * 1024 + rr] = (_Float16)(v[j] - (float)h);
    }
  }
}

// LSTM activation; sums NP K-split partials (f32 or fp16 per H16).
// ATT variant also fills hatt_h, conc hi/lo slot, and X2h slots 1024/3072.
template<int NP, bool H16, bool ATT>
__global__ __launch_bounds__(256) void lstm_act_kernel(
    const void* __restrict__ gp, const float* __restrict__ bih,
    const float* __restrict__ bhh, const float* __restrict__ cin,
    float* __restrict__ hOut, float* __restrict__ cOut,
    _Float16* __restrict__ hatt_h, _Float16* __restrict__ conch,
    _Float16* __restrict__ concl, _Float16* __restrict__ x2h,
    const float* __restrict__ sh, float* __restrict__ hOut2)
{
  const long S = 2097152;   // 512*4096
  int i = blockIdx.x * 256 + threadIdx.x;   // [0, 512*1024)
  int b = i >> 10, rr = i & 1023;
  long gb = (long)b * 4096;
  float g4[4];
#pragma unroll
  for (int q = 0; q < 4; q++) {
    float s = 0.f;
#pragma unroll
    for (int z = 0; z < NP; z++) {
      long off = (long)z * S + gb + q * 1024 + rr;
      s += H16 ? (float)((const _Float16*)gp)[off] : ((const float*)gp)[off];
    }
    g4[q] = s + bih[q * 1024 + rr] + bhh[q * 1024 + rr];
  }
  float c  = cin[i];
  float c2 = fast_sigmoid(g4[1]) * c + fast_sigmoid(g4[0]) * fast_tanh(g4[2]);
  float h2 = fast_sigmoid(g4[3]) * fast_tanh(c2);
  hOut[i] = h2;
  cOut[i] = c2;
  if (hOut2) hOut2[i] = h2;
  if (ATT) {
    _Float16 hh = (_Float16)h2;
    hatt_h[i] = hh;
    conch[(long)b * 2048 + 1024 + rr] = hh;
    concl[(long)b * 2048 + 1024 + rr] = (_Float16)(h2 - (float)hh);
    x2h[(long)b * 4096 + 1024 + rr] = hh;
    x2h[(long)b * 4096 + 3072 + rr] = (_Float16)sh[524288 + i];
  }
}

// ---------------------------------------------------------------------------
// fused attention-1: per block b -- scores (tanh-dot over p_att, atth partials
// hoisted once per block) -> softmax -> weighted sum over att_feats.
__global__ __launch_bounds__(256) void att1_kernel(
    const float* __restrict__ pf, const float* __restrict__ atthp,
    const float* __restrict__ bh,
    const float* __restrict__ walpha, const float* __restrict__ balpha,
    const float* __restrict__ feats,
    _Float16* __restrict__ conch, _Float16* __restrict__ concl,
    _Float16* __restrict__ x2h)
{
  __shared__ float w[200];
  int b = blockIdx.x, t = threadIdx.x;
  int lane = t & 63, wv = t >> 6;

  // hoisted per-lane additive term: sum of 4 atth partials + bh2att1
  f32x4 add0 = *(const f32x4*)(bh + lane * 8);
  f32x4 add1 = *(const f32x4*)(bh + lane * 8 + 4);
#pragma unroll
  for (int z = 0; z < 4; z++) {
    const float* ap = atthp + (long)z * 524288 + (long)b * 1024 + lane * 8;
    add0 += *(const f32x4*)(ap);
    add1 += *(const f32x4*)(ap + 4);
  }
  f32x4 wv0 = *(const f32x4*)(walpha + lane * 8);
  f32x4 wv1 = *(const f32x4*)(walpha + lane * 8 + 4);

  // phase 1: scores (each wave handles rows wv, wv+4, ...)
  for (int s = wv; s < 196; s += 4) {
    const float* p = pf + ((long)b * 196 + s) * 512 + lane * 8;
    f32x4 p0 = *(const f32x4*)(p);
    f32x4 p1 = *(const f32x4*)(p + 4);
    float acc = 0.f;
#pragma unroll
    for (int j = 0; j < 4; j++) {
      acc += fast_tanh(p0[j] + add0[j]) * wv0[j];
      acc += fast_tanh(p1[j] + add1[j]) * wv1[j];
    }
#pragma unroll
    for (int off = 32; off; off >>= 1) acc += __shfl_xor(acc, off);
    if (lane == 0) w[s] = acc + balpha[0];
  }
  __syncthreads();

  // phase 2: softmax in LDS
  float mx = -3.0e38f;
  for (int i = 0; i < 196; i++) mx = fmaxf(mx, w[i]);
  float sum = 0.f;
  for (int i = 0; i < 196; i++) sum += __expf(w[i] - mx);
  float inv = 1.f / sum;
  float myw = (t < 196) ? __expf(w[t] - mx) * inv : 0.f;
  __syncthreads();
  if (t < 196) w[t] = myw;
  __syncthreads();

  // phase 3: weighted sum (thread t owns cols t*4..t*4+3)
  f32x4 acc = (f32x4){0.f, 0.f, 0.f, 0.f};
  const float* fb = feats + (long)b * 200704 + t * 4;
  for (int s0i = 0; s0i < 192; s0i += 8) {
    f32x4 v[8];
#pragma unroll
    for (int u = 0; u < 8; u++) v[u] = *(const f32x4*)(fb + (long)(s0i + u) * 1024);
#pragma unroll
    for (int u = 0; u < 8; u++) {
      float ws = w[s0i + u];
#pragma unroll
      for (int j = 0; j < 4; j++) acc[j] += ws * v[u][j];
    }
  }
#pragma unroll
  for (int u = 192; u < 196; u++) {
    float ws = w[u];
    f32x4 v = *(const f32x4*)(fb + (long)u * 1024);
#pragma unroll
    for (int j = 0; j < 4; j++) acc[j] += ws * v[j];
  }
  half4 h, l;
#pragma unroll
  for (int j = 0; j < 4; j++) { h[j] = (_Float16)acc[j]; l[j] = (_Float16)(acc[j] - (float)h[j]); }
  *(half4*)&conch[(long)b * 2048 + t * 4] = h;
  *(half4*)&concl[(long)b * 2048 + t * 4] = l;
  *(half4*)&x2h[(long)b * 4096 + 2048 + t * 4] = h;
}

// ---------------------------------------------------------------------------
// fused top-36 + gather: cooperative partial-sum into LDS, wave-0 selection,
// then all 256 threads gather + fp16-convert the 36 selected rows.
template<int NP>
__global__ __launch_bounds__(256) void topk_gather_kernel(
    const float* __restrict__ vfp, const float* __restrict__ b_vf,
    const float* __restrict__ feats, _Float16* __restrict__ dst)
{
  __shared__ float sv[196];
  __shared__ int six[36];
  int b = blockIdx.x, t = threadIdx.x;

  if (t < 196) {
    float s = b_vf[t];
#pragma unroll
    for (int z = 0; z < NP; z++) s += vfp[(long)z * 100352 + b * 196 + t];
    sv[t] = s;
  }
  __syncthreads();

  if (t < 64) {
    float v[4];
#pragma unroll
    for (int j = 0; j < 4; j++) {
      int s = t + 64 * j;
      v[j] = (s < 196) ? sv[s] : -3.0e38f;
    }
    for (int it = 0; it < 36; it++) {
      float bv = -3.0e38f; int bs = 1 << 20;
#pragma unroll
      for (int j = 0; j < 4; j++) {
        int s = t + 64 * j;
        if (v[j] > bv) { bv = v[j]; bs = s; }
      }
#pragma unroll
      for (int off = 32; off; off >>= 1) {
        float ov = __shfl_xor(bv, off);
        int   os = __shfl_xor(bs, off);
        if (ov > bv || (ov == bv && os < bs)) { bv = ov; bs = os; }
      }
      if ((bs & 63) == t) v[bs >> 6] = -3.0e38f;
      if (t == 0) six[it] = bs;
    }
  }
  __syncthreads();

  for (int j = 0; j < 36; j++) {
    int s = six[j];
    f32x4 v = *(const f32x4*)(feats + ((long)b * 196 + s) * 1024 + t * 4);
    half4 h;
#pragma unroll
    for (int q = 0; q < 4; q++) h[q] = (_Float16)v[q];
    *(half4*)&dst[((long)b * 36 + j) * 1024 + t * 4] = h;
  }
}

// merged attention-2: scores + softmax + weighted sum (atth2 from 4 partials)
__global__ __launch_bounds__(256) void vfatt_kernel(
    const _Float16* __restrict__ pvf16, const float* __restrict__ atthp,
    const float* __restrict__ bh2att2, const float* __restrict__ b_pvf,
    const float* __restrict__ walpha2, const float* __restrict__ balpha2,
    const _Float16* __restrict__ arr1h, _Float16* __restrict__ x2h)
{
  __shared__ float w[40];
  int b = blockIdx.x, tid = threadIdx.x;
  int lane = tid & 63, wv = tid >> 6;

  float add[8], wal[8];
#pragma unroll
  for (int u = 0; u < 8; u++) {
    int a = lane * 8 + u;
    add[u] = bh2att2[a] + b_pvf[a];
    wal[u] = walpha2[a];
  }
#pragma unroll
  for (int z = 0; z < 4; z++) {
    const float* ap = atthp + (long)z * 524288 + (long)b * 1024 + 512 + lane * 8;
#pragma unroll
    for (int u = 0; u < 8; u++) add[u] += ap[u];
  }
  for (int j = wv; j < 36; j += 4) {
    half8 hv = *(const half8*)&pvf16[((long)b * 36 + j) * 512 + lane * 8];
    float acc = 0.f;
#pragma unroll
    for (int u = 0; u < 8; u++)
      acc += fast_tanh((float)hv[u] + add[u]) * wal[u];
#pragma unroll
    for (int off = 32; off; off >>= 1) acc += __shfl_xor(acc, off);
    if (lane == 0) w[j] = acc + balpha2[0];
  }
  __syncthreads();
  float mx = -3.0e38f;
  for (int i = 0; i < 36; i++) mx = fmaxf(mx, w[i]);
  float sum = 0.f;
  for (int i = 0; i < 36; i++) sum += __expf(w[i] - mx);
  float inv = 1.f / sum;
  __syncthreads();
  if (tid < 36) w[tid] = __expf(w[tid] - mx) * inv;
  __syncthreads();
  f32x4 acc = (f32x4){0.f, 0.f, 0.f, 0.f};
  const _Float16* fb = arr1h + (long)b * 36 * 1024 + tid * 4;
#pragma unroll 4
  for (int s = 0; s < 36; s++) {
    float ws = w[s];
    half4 v = *(const half4*)(fb + (long)s * 1024);
#pragma unroll
    for (int j = 0; j < 4; j++) acc[j] += ws * (float)v[j];
  }
  half4 h;
#pragma unroll
  for (int j = 0; j < 4; j++) h[j] = (_Float16)acc[j];
  *(half4*)&x2h[(long)b * 4096 + tid * 4] = h;
}

// ---------------------------------------------------------------------------
extern "C" void kernel_launch(void* const* d_in, const int* in_sizes, int n_in,
                              void* d_out, int out_size, void* d_ws, size_t ws_size,
                              hipStream_t stream) {
  const float* xt        = (const float*)d_in[0];
  const float* fc_feats  = (const float*)d_in[1];
  const float* att_feats = (const float*)d_in[2];
  const float* p_att     = (const float*)d_in[3];
  const float* state_h   = (const float*)d_in[4];
  const float* state_c   = (const float*)d_in[5];
  const float* b_ih_att  = (const float*)d_in[7];
  const float* b_hh_att  = (const float*)d_in[9];
  const float* b_ih_lang = (const float*)d_in[11];
  const float* b_hh_lang = (const float*)d_in[13];
  const float* bh2att1   = (const float*)d_in[15];
  const float* Walpha1   = (const float*)d_in[16];
  const float* balpha1   = (const float*)d_in[17];
  const float* bh2att2   = (const float*)d_in[19];
  const float* Walpha2   = (const float*)d_in[20];
  const float* balpha2   = (const float*)d_in[21];
  const float* b_vf      = (const float*)d_in[23];
  const float* b_pvf     = (const float*)d_in[25];

  float* out = (float*)d_out;
  float* W = (float*)d_ws;   // pool, f32-unit offsets; flat layout

  _Float16* WcAh   = (_Float16*)(W + 0);         // [4096][4096] fp16 hi
  _Float16* WcAl   = (_Float16*)(W + 8388608);   // [4096][4096] fp16 lo
  _Float16* WcLh   = (_Float16*)(W + 16777216);  // [4096][4096] fp16 (lang)
  _Float16* X1h    = (_Float16*)(W + 25165824);  // [512][4096]
  _Float16* X1l    = (_Float16*)(W + 26214400);  // [512][4096]
  float*    g1p    = W + 27262976;               // [4][512][4096] f32
  _Float16* hatt_h = (_Float16*)(W + 35651584);  // [512][1024]
  _Float16* W12h   = (_Float16*)(W + 35913728);  // [1024][1024]
  _Float16* Wvfh   = (_Float16*)(W + 36438016);  // [196][2048]
  _Float16* Wvfl   = (_Float16*)(W + 36638720);  // [196][2048]
  _Float16* Wpvfh  = (_Float16*)(W + 36839424);  // [512][1024]
  float*    atthp  = W + 37101568;               // [4][512][1024] f32
  _Float16* conch  = (_Float16*)(W + 39198720);  // [512][2048]
  _Float16* concl  = (_Float16*)(W + 39723008);  // [512][2048]
  _Float16* X2h    = (_Float16*)(W + 40247296);  // [512][4096]
  float*    vfhap  = W + 41396224;               // [16][512][196] f32
  _Float16* arr1h  = (_Float16*)(W + 43020288);  // [18432][1024]
  _Float16* pvf16  = (_Float16*)(W + 52457472);  // [18432][512]
  _Float16* g2ph   = (_Float16*)(W + 57176064);  // [4][512][4096] fp16

  float* out_h0 = out + 524288;
  float* out_h1 = out + 2 * 524288;
  float* out_c0 = out + 3 * 524288;
  float* out_c1 = out + 4 * 524288;

  // 1. prep: all weight converts + X1 hi/lo pack (one kernel)
  prep_kernel<<<36744, 256, 0, stream>>>(
      (const float*)d_in[6], (const float*)d_in[8],
      (const float*)d_in[10], (const float*)d_in[12],
      (const float*)d_in[14], (const float*)d_in[18],
      (const float*)d_in[22], (const float*)d_in[24],
      xt, fc_feats, state_h,
      WcAh, WcAl, WcLh, W12h, Wvfh, Wvfl, Wpvfh, X1h, X1l);

  // 2. att-LSTM gates: split-3, z=4 (512 blocks = 2/CU), counted-vmcnt pipeline
  gemm16<3, 0, 0, 0><<<dim3(32, 4, 4), 256, 0, stream>>>(
      X1h, X1l, 4096, WcAh, WcAl, 4096, g1p, 4096, 2097152, 4096, 1024);

  // 3. att-LSTM activation (sums 4 f32 partials; fills conc/X2h slots)
  lstm_act_kernel<4, false, true><<<2048, 256, 0, stream>>>(
      g1p, b_ih_att, b_hh_att, state_c, out_h0, out_c0,
      hatt_h, conch, concl, X2h, state_h, nullptr);

  // 4. fused atth1|atth2 projection, z=4 (partials consumed by att1/vfatt)
  gemm16<1, 0, 0, 0><<<dim3(8, 4, 4), 256, 0, stream>>>(
      hatt_h, nullptr, 1024, W12h, nullptr, 1024, atthp, 1024, 524288, 1024, 256);

  // 5. fused attention-1: scores + softmax + weighted sum
  att1_kernel<<<512, 256, 0, stream>>>(
      p_att, atthp, bh2att1, Walpha1, balpha1, att_feats, conch, concl, X2h);

  // 6. vf logits, split-3, z=16 (128 blocks; partials summed in topk)
  gemm16<3, 0, 1, 0><<<dim3(2, 4, 16), 256, 0, stream>>>(
      conch, concl, 2048, Wvfh, Wvfl, 2048, vfhap, 196, 100352, 196, 128);

  // 7. fused top-36 + gather + fp16 convert
  topk_gather_kernel<16><<<512, 256, 0, stream>>>(vfhap, b_vf, att_feats, arr1h);

  // 8. p_vf_feats (fp16 out); SWAPXY: same-M blocks stride 144 (=0 mod 8)
  gemm16<1, 1, 0, 1><<<dim3(144, 4, 1), 256, 0, stream>>>(
      arr1h, nullptr, 1024, Wpvfh, nullptr, 1024, pvf16, 512, 0, 512, 1024);

  // 9. attention-2 merged: scores + softmax + weighted sum -> X2h[:,0:1024]
  vfatt_kernel<<<512, 256, 0, stream>>>(
      pvf16, atthp, bh2att2, b_pvf, Walpha2, balpha2, arr1h, X2h);

  // 10. lang-LSTM gates: plain fp16, z=4, fp16 partials
  gemm16<1, 1, 0, 0><<<dim3(32, 4, 4), 256, 0, stream>>>(
      X2h, nullptr, 4096, WcLh, nullptr, 4096, g2ph, 4096, 2097152, 4096, 1024);

  // 11. lang-LSTM activation -> output (sums 4 fp16 partials)
  lstm_act_kernel<4, true, false><<<2048, 256, 0, stream>>>(
      g2ph, b_ih_lang, b_hh_lang, state_c + 524288, out, out_c1,
      nullptr, nullptr, nullptr, nullptr, nullptr, out_h1);
}

// Round 10
// 412.581 us; speedup vs baseline: 1.0382x; 1.0038x over previous
//
#include <hip/hip_runtime.h>

typedef __attribute__((ext_vector_type(4))) float f32x4;
typedef __attribute__((ext_vector_type(8))) _Float16 half8;
typedef __attribute__((ext_vector_type(4))) _Float16 half4;

__device__ __forceinline__ float fast_tanh(float x) {
  float e = __expf(2.f * x);
  return 1.f - 2.f / (e + 1.f);
}
__device__ __forceinline__ float fast_sigmoid(float x) {
  return 1.f / (1.f + __expf(-x));
}

__device__ __forceinline__ void gl_lds16(const _Float16* g, _Float16* l) {
  __builtin_amdgcn_global_load_lds(
      (const __attribute__((address_space(1))) void*)g,
      (__attribute__((address_space(3))) void*)l, 16, 0, 0);
}

// ---------------------------------------------------------------------------
// ROUND-5 MEASURED-BEST GEMM (do not touch): C[M,N] = A[M,K] @ B[N,K]^T,
// fp16 (hi/lo split-3 optional), f32 accum. 128x128 tile, 4 waves, BK=32,
// double-buffered LDS, counted-vmcnt pipeline, 16x16x32 MFMA.
// ---------------------------------------------------------------------------
template<int SPLIT, int OUT16, int NGUARD, int SWAPXY>
__global__ __launch_bounds__(256) void gemm16(
    const _Float16* __restrict__ Ahp, const _Float16* __restrict__ Alp, int lda,
    const _Float16* __restrict__ Bhp, const _Float16* __restrict__ Blp, int ldb,
    void* __restrict__ Cp, int ldc, long czstride,
    int N, int Kc)
{
  __shared__ _Float16 sAh[2][128 * 32];
  __shared__ _Float16 sBh[2][128 * 32];
  __shared__ _Float16 sAl[SPLIT == 3 ? 2 : 1][SPLIT == 3 ? 128 * 32 : 8];
  __shared__ _Float16 sBl[SPLIT == 3 ? 2 : 1][SPLIT == 3 ? 128 * 32 : 8];

  const int tid = threadIdx.x, lane = tid & 63, wid = tid >> 6;
  const int wm = wid >> 1, wn = wid & 1;
  const int l16 = lane & 15, k8 = lane >> 4;
  const int sr = lane >> 2;
  const int scol = ((lane & 3) ^ ((lane >> 3) & 3)) * 8;   // swizzled src col
  const int koff = ((k8 ^ ((lane >> 1) & 3))) * 8;         // swizzled read off

  const int  kt0   = blockIdx.z * Kc;
  const long abase = (long)(SWAPXY ? blockIdx.x : blockIdx.y) * 128;
  const long bbase = (long)(SWAPXY ? blockIdx.y : blockIdx.x) * 128;

  const int r0 = wid * 32 + sr;
  const int r1 = wid * 32 + 16 + sr;
  long br0 = bbase + r0, br1 = bbase + r1;
  if (NGUARD) {
    if (br0 > N - 1) br0 = N - 1;
    if (br1 > N - 1) br1 = N - 1;
  }

  const _Float16* ga0 = Ahp + (abase + r0) * (long)lda + kt0 + scol;
  const _Float16* ga1 = Ahp + (abase + r1) * (long)lda + kt0 + scol;
  const _Float16* gb0 = Bhp + br0 * (long)ldb + kt0 + scol;
  const _Float16* gb1 = Bhp + br1 * (long)ldb + kt0 + scol;
  const _Float16* la0 = SPLIT == 3 ? Alp + (abase + r0) * (long)lda + kt0 + scol : nullptr;
  const _Float16* la1 = SPLIT == 3 ? Alp + (abase + r1) * (long)lda + kt0 + scol : nullptr;
  const _Float16* lb0 = SPLIT == 3 ? Blp + br0 * (long)ldb + kt0 + scol : nullptr;
  const _Float16* lb1 = SPLIT == 3 ? Blp + br1 * (long)ldb + kt0 + scol : nullptr;

  const int e0 = (wid * 32) * 32;        // wave-uniform LDS elem base, chunk 0
  const int e1 = (wid * 32 + 16) * 32;   // chunk 1

  f32x4 acc[4][4];
#pragma unroll
  for (int i = 0; i < 4; i++)
#pragma unroll
    for (int j = 0; j < 4; j++) acc[i][j] = (f32x4){0.f, 0.f, 0.f, 0.f};

  auto STAGE = [&](int buf, int kk) {
    gl_lds16(ga0 + kk, &sAh[buf][e0]);
    gl_lds16(ga1 + kk, &sAh[buf][e1]);
    gl_lds16(gb0 + kk, &sBh[buf][e0]);
    gl_lds16(gb1 + kk, &sBh[buf][e1]);
    if (SPLIT == 3) {
      gl_lds16(la0 + kk, &sAl[buf][e0]);
      gl_lds16(la1 + kk, &sAl[buf][e1]);
      gl_lds16(lb0 + kk, &sBl[buf][e0]);
      gl_lds16(lb1 + kk, &sBl[buf][e1]);
    }
  };

  STAGE(0, 0);

  const int nst = Kc >> 5;
  for (int t = 0; t < nst; t++) {
    const int buf = t & 1;
    if (t + 1 < nst) {
      STAGE(buf ^ 1, (t + 1) * 32);
      // wait only for PREV step's loads (the just-issued stay in flight)
      if (SPLIT == 3) asm volatile("s_waitcnt vmcnt(8)" ::: "memory");
      else            asm volatile("s_waitcnt vmcnt(4)" ::: "memory");
    } else {
      asm volatile("s_waitcnt vmcnt(0)" ::: "memory");
    }
    __builtin_amdgcn_sched_barrier(0);
    __builtin_amdgcn_s_barrier();          // all waves' buf loads visible
    __builtin_amdgcn_sched_barrier(0);

    half8 ah[4], bh[4];
#pragma unroll
    for (int m = 0; m < 4; m++)
      ah[m] = *(const half8*)&sAh[buf][(wm * 64 + m * 16 + l16) * 32 + koff];
#pragma unroll
    for (int n = 0; n < 4; n++)
      bh[n] = *(const half8*)&sBh[buf][(wn * 64 + n * 16 + l16) * 32 + koff];
#pragma unroll
    for (int m = 0; m < 4; m++)
#pragma unroll
      for (int n = 0; n < 4; n++)
        acc[m][n] = __builtin_amdgcn_mfma_f32_16x16x32_f16(ah[m], bh[n], acc[m][n], 0, 0, 0);
    if (SPLIT == 3) {
      half8 al[4], bl[4];
#pragma unroll
      for (int m = 0; m < 4; m++)
        al[m] = *(const half8*)&sAl[buf][(wm * 64 + m * 16 + l16) * 32 + koff];
#pragma unroll
      for (int n = 0; n < 4; n++)
        bl[n] = *(const half8*)&sBl[buf][(wn * 64 + n * 16 + l16) * 32 + koff];
#pragma unroll
      for (int m = 0; m < 4; m++)
#pragma unroll
        for (int n = 0; n < 4; n++) {
          acc[m][n] = __builtin_amdgcn_mfma_f32_16x16x32_f16(al[m], bh[n], acc[m][n], 0, 0, 0);
          acc[m][n] = __builtin_amdgcn_mfma_f32_16x16x32_f16(ah[m], bl[n], acc[m][n], 0, 0, 0);
        }
    }
    __builtin_amdgcn_sched_barrier(0);
    __builtin_amdgcn_s_barrier();          // WAR guard: reads of buf done
    __builtin_amdgcn_sched_barrier(0);
  }

  const long czoff = (long)blockIdx.z * czstride;
#pragma unroll
  for (int m = 0; m < 4; m++)
#pragma unroll
    for (int n = 0; n < 4; n++) {
      const long row0 = abase + wm * 64 + m * 16 + (lane >> 4) * 4;
      const long col  = bbase + wn * 64 + n * 16 + l16;
      if (!NGUARD || col < N) {
#pragma unroll
        for (int j = 0; j < 4; j++) {
          const long idx = (row0 + j) * (long)ldc + col + czoff;
          if (OUT16) ((_Float16*)Cp)[idx] = (_Float16)acc[m][n][j];
          else       ((float*)Cp)[idx] = acc[m][n][j];
        }
      }
    }
}

// ---------------------------------------------------------------------------
// prep: all weight converts + X1 hi/lo pack in ONE kernel (block-range dispatch)
__global__ __launch_bounds__(256) void prep_kernel(
    const float* __restrict__ WihA, const float* __restrict__ WhhA,
    const float* __restrict__ WihL, const float* __restrict__ WhhL,
    const float* __restrict__ Wh1, const float* __restrict__ Wh2,
    const float* __restrict__ Wvf, const float* __restrict__ Wpvf,
    const float* __restrict__ xt, const float* __restrict__ fc,
    const float* __restrict__ sh,
    _Float16* __restrict__ WcAh, _Float16* __restrict__ WcAl,
    _Float16* __restrict__ WcLh, _Float16* __restrict__ W12h,
    _Float16* __restrict__ Wvfh, _Float16* __restrict__ Wvfl,
    _Float16* __restrict__ Wpvfh,
    _Float16* __restrict__ X1h, _Float16* __restrict__ X1l)
{
  int bi = blockIdx.x, t = threadIdx.x;
  if (bi < 16384) {                       // Wc_att [4096][4096] hi+lo
    long e = ((long)bi * 256 + t) * 4;
    int row = (int)(e >> 12), col = (int)(e & 4095);
    const float* src = (col < 3072) ? WihA + (long)row * 3072 + col
                                    : WhhA + (long)row * 1024 + (col - 3072);
    f32x4 v = *(const f32x4*)src;
    half4 h, l;
#pragma unroll
    for (int j = 0; j < 4; j++) { h[j] = (_Float16)v[j]; l[j] = (_Float16)(v[j] - (float)h[j]); }
    *(half4*)&WcAh[e] = h;
    *(half4*)&WcAl[e] = l;
  } else if (bi < 32768) {                // Wc_lang [4096][4096] hi only
    long e = ((long)(bi - 16384) * 256 + t) * 4;
    int row = (int)(e >> 12), col = (int)(e & 4095);
    const float* src = (col < 3072) ? WihL + (long)row * 3072 + col
                                    : WhhL + (long)row * 1024 + (col - 3072);
    f32x4 v = *(const f32x4*)src;
    half4 h;
#pragma unroll
    for (int j = 0; j < 4; j++) h[j] = (_Float16)v[j];
    *(half4*)&WcLh[e] = h;
  } else if (bi < 33792) {                // Whh12 [1024][1024]
    long e = ((long)(bi - 32768) * 256 + t) * 4;
    int row = (int)(e >> 10), col = (int)(e & 1023);
    const float* src = (row < 512) ? Wh1 + (long)row * 1024 + col
                                   : Wh2 + (long)(row - 512) * 1024 + col;
    f32x4 v = *(const f32x4*)src;
    half4 h;
#pragma unroll
    for (int j = 0; j < 4; j++) h[j] = (_Float16)v[j];
    *(half4*)&W12h[e] = h;
  } else if (bi < 34184) {                // Wvf [196][2048] hi+lo
    long e = ((long)(bi - 33792) * 256 + t) * 4;
    f32x4 v = *(const f32x4*)(Wvf + e);
    half4 h, l;
#pragma unroll
    for (int j = 0; j < 4; j++) { h[j] = (_Float16)v[j]; l[j] = (_Float16)(v[j] - (float)h[j]); }
    *(half4*)&Wvfh[e] = h;
    *(half4*)&Wvfl[e] = l;
  } else if (bi < 34696) {                // Wpvf [512][1024]
    long e = ((long)(bi - 34184) * 256 + t) * 4;
    f32x4 v = *(const f32x4*)(Wpvf + e);
    half4 h;
#pragma unroll
    for (int j = 0; j < 4; j++) h[j] = (_Float16)v[j];
    *(half4*)&Wpvfh[e] = h;
  } else {                                // X1 pack hi/lo
    int i = (bi - 34696) * 256 + t;       // [0, 512*1024)
    int b = i >> 10, rr = i & 1023;
    long base = (long)b * 4096;
    float v[4];
    v[0] = sh[524288 + i];   // prev_h = state_h[1]
    v[1] = fc[i];
    v[2] = xt[i];
    v[3] = sh[i];            // state_h[0] (hidden)
#pragma unroll
    for (int j = 0; j < 4; j++) {
      _Float16 h = (_Float16)v[j];
      X1h[base + j * 1024 + rr] = h;
      X1l[base + j * 1024 + rr] = (_Float16)(v[j] - (float)h);
    }
  }
}

// LSTM activation; sums NP K-split partials (f32 or fp16 per H16).
// ATT variant also fills hatt_h, conc hi/lo slot, and X2h slots 1024/3072.
template<int NP, bool H16, bool ATT>
__global__ __launch_bounds__(256) void lstm_act_kernel(
    const void* __restrict__ gp, const float* __restrict__ bih,
    const float* __restrict__ bhh, const float* __restrict__ cin,
    float* __restrict__ hOut, float* __restrict__ cOut,
    _Float16* __restrict__ hatt_h, _Float16* __restrict__ conch,
    _Float16* __restrict__ concl, _Float16* __restrict__ x2h,
    const float* __restrict__ sh, float* __restrict__ hOut2)
{
  const long S = 2097152;   // 512*4096
  int i = blockIdx.x * 256 + threadIdx.x;   // [0, 512*1024)
  int b = i >> 10, rr = i & 1023;
  long gb = (long)b * 4096;
  float g4[4];
#pragma unroll
  for (int q = 0; q < 4; q++) {
    float s = 0.f;
#pragma unroll
    for (int z = 0; z < NP; z++) {
      long off = (long)z * S + gb + q * 1024 + rr;
      s += H16 ? (float)((const _Float16*)gp)[off] : ((const float*)gp)[off];
    }
    g4[q] = s + bih[q * 1024 + rr] + bhh[q * 1024 + rr];
  }
  float c  = cin[i];
  float c2 = fast_sigmoid(g4[1]) * c + fast_sigmoid(g4[0]) * fast_tanh(g4[2]);
  float h2 = fast_sigmoid(g4[3]) * fast_tanh(c2);
  hOut[i] = h2;
  cOut[i] = c2;
  if (hOut2) hOut2[i] = h2;
  if (ATT) {
    _Float16 hh = (_Float16)h2;
    hatt_h[i] = hh;
    conch[(long)b * 2048 + 1024 + rr] = hh;
    concl[(long)b * 2048 + 1024 + rr] = (_Float16)(h2 - (float)hh);
    x2h[(long)b * 4096 + 1024 + rr] = hh;
    x2h[(long)b * 4096 + 3072 + rr] = (_Float16)sh[524288 + i];
  }
}

// ---------------------------------------------------------------------------
// fused attention-1: per block b -- scores (tanh-dot over p_att, atth partials
// hoisted once per block; TWO rows in flight per wave-iter for MLP) ->
// softmax -> weighted sum over att_feats.
__global__ __launch_bounds__(256) void att1_kernel(
    const float* __restrict__ pf, const float* __restrict__ atthp,
    const float* __restrict__ bh,
    const float* __restrict__ walpha, const float* __restrict__ balpha,
    const float* __restrict__ feats,
    _Float16* __restrict__ conch, _Float16* __restrict__ concl,
    _Float16* __restrict__ x2h)
{
  __shared__ float w[200];
  int b = blockIdx.x, t = threadIdx.x;
  int lane = t & 63, wv = t >> 6;

  // hoisted per-lane additive term: sum of 4 atth partials + bh2att1
  f32x4 add0 = *(const f32x4*)(bh + lane * 8);
  f32x4 add1 = *(const f32x4*)(bh + lane * 8 + 4);
#pragma unroll
  for (int z = 0; z < 4; z++) {
    const float* ap = atthp + (long)z * 524288 + (long)b * 1024 + lane * 8;
    add0 += *(const f32x4*)(ap);
    add1 += *(const f32x4*)(ap + 4);
  }
  f32x4 wv0 = *(const f32x4*)(walpha + lane * 8);
  f32x4 wv1 = *(const f32x4*)(walpha + lane * 8 + 4);

  // phase 1: scores; wave handles row pairs (s, s+4), s = wv, wv+8, ...
  for (int s = wv; s < 196; s += 8) {
    const int s2 = s + 4;
    const bool has2 = (s2 < 196);
    const float* p = pf + ((long)b * 196 + s) * 512 + lane * 8;
    const float* q = pf + ((long)b * 196 + (has2 ? s2 : s)) * 512 + lane * 8;
    f32x4 p0 = *(const f32x4*)(p);
    f32x4 p1 = *(const f32x4*)(p + 4);
    f32x4 q0 = *(const f32x4*)(q);
    f32x4 q1 = *(const f32x4*)(q + 4);
    float acc = 0.f, acc2 = 0.f;
#pragma unroll
    for (int j = 0; j < 4; j++) {
      acc  += fast_tanh(p0[j] + add0[j]) * wv0[j];
      acc  += fast_tanh(p1[j] + add1[j]) * wv1[j];
      acc2 += fast_tanh(q0[j] + add0[j]) * wv0[j];
      acc2 += fast_tanh(q1[j] + add1[j]) * wv1[j];
    }
#pragma unroll
    for (int off = 32; off; off >>= 1) {
      acc  += __shfl_xor(acc, off);
      acc2 += __shfl_xor(acc2, off);
    }
    if (lane == 0) {
      w[s] = acc + balpha[0];
      if (has2) w[s2] = acc2 + balpha[0];
    }
  }
  __syncthreads();

  // phase 2: softmax in LDS
  float mx = -3.0e38f;
  for (int i = 0; i < 196; i++) mx = fmaxf(mx, w[i]);
  float sum = 0.f;
  for (int i = 0; i < 196; i++) sum += __expf(w[i] - mx);
  float inv = 1.f / sum;
  float myw = (t < 196) ? __expf(w[t] - mx) * inv : 0.f;
  __syncthreads();
  if (t < 196) w[t] = myw;
  __syncthreads();

  // phase 3: weighted sum (thread t owns cols t*4..t*4+3)
  f32x4 acc = (f32x4){0.f, 0.f, 0.f, 0.f};
  const float* fb = feats + (long)b * 200704 + t * 4;
  for (int s0i = 0; s0i < 192; s0i += 8) {
    f32x4 v[8];
#pragma unroll
    for (int u = 0; u < 8; u++) v[u] = *(const f32x4*)(fb + (long)(s0i + u) * 1024);
#pragma unroll
    for (int u = 0; u < 8; u++) {
      float ws = w[s0i + u];
#pragma unroll
      for (int j = 0; j < 4; j++) acc[j] += ws * v[u][j];
    }
  }
#pragma unroll
  for (int u = 192; u < 196; u++) {
    float ws = w[u];
    f32x4 v = *(const f32x4*)(fb + (long)u * 1024);
#pragma unroll
    for (int j = 0; j < 4; j++) acc[j] += ws * v[j];
  }
  half4 h, l;
#pragma unroll
  for (int j = 0; j < 4; j++) { h[j] = (_Float16)acc[j]; l[j] = (_Float16)(acc[j] - (float)h[j]); }
  *(half4*)&conch[(long)b * 2048 + t * 4] = h;
  *(half4*)&concl[(long)b * 2048 + t * 4] = l;
  *(half4*)&x2h[(long)b * 4096 + 2048 + t * 4] = h;
}

// ---------------------------------------------------------------------------
// fused top-36 + gather: cooperative partial-sum into LDS, wave-0 selection,
// then all 256 threads gather + fp16-convert (4 rows in flight for MLP).
template<int NP>
__global__ __launch_bounds__(256) void topk_gather_kernel(
    const float* __restrict__ vfp, const float* __restrict__ b_vf,
    const float* __restrict__ feats, _Float16* __restrict__ dst)
{
  __shared__ float sv[196];
  __shared__ int six[36];
  int b = blockIdx.x, t = threadIdx.x;

  if (t < 196) {
    float s = b_vf[t];
#pragma unroll
    for (int z = 0; z < NP; z++) s += vfp[(long)z * 100352 + b * 196 + t];
    sv[t] = s;
  }
  __syncthreads();

  if (t < 64) {
    float v[4];
#pragma unroll
    for (int j = 0; j < 4; j++) {
      int s = t + 64 * j;
      v[j] = (s < 196) ? sv[s] : -3.0e38f;
    }
    for (int it = 0; it < 36; it++) {
      float bv = -3.0e38f; int bs = 1 << 20;
#pragma unroll
      for (int j = 0; j < 4; j++) {
        int s = t + 64 * j;
        if (v[j] > bv) { bv = v[j]; bs = s; }
      }
#pragma unroll
      for (int off = 32; off; off >>= 1) {
        float ov = __shfl_xor(bv, off);
        int   os = __shfl_xor(bs, off);
        if (ov > bv || (ov == bv && os < bs)) { bv = ov; bs = os; }
      }
      if ((bs & 63) == t) v[bs >> 6] = -3.0e38f;
      if (t == 0) six[it] = bs;
    }
  }
  __syncthreads();

  for (int j = 0; j < 36; j += 4) {
    f32x4 v[4];
#pragma unroll
    for (int q = 0; q < 4; q++) {
      int s = six[j + q];
      v[q] = *(const f32x4*)(feats + ((long)b * 196 + s) * 1024 + t * 4);
    }
#pragma unroll
    for (int q = 0; q < 4; q++) {
      half4 h;
#pragma unroll
      for (int r = 0; r < 4; r++) h[r] = (_Float16)v[q][r];
      *(half4*)&dst[((long)b * 36 + j + q) * 1024 + t * 4] = h;
    }
  }
}

// merged attention-2: scores + softmax + weighted sum (atth2 from 4 partials)
__global__ __launch_bounds__(256) void vfatt_kernel(
    const _Float16* __restrict__ pvf16, const float* __restrict__ atthp,
    const float* __restrict__ bh2att2, const float* __restrict__ b_pvf,
    const float* __restrict__ walpha2, const float* __restrict__ balpha2,
    const _Float16* __restrict__ arr1h, _Float16* __restrict__ x2h)
{
  __shared__ float w[40];
  int b = blockIdx.x, tid = threadIdx.x;
  int lane = tid & 63, wv = tid >> 6;

  float add[8], wal[8];
#pragma unroll
  for (int u = 0; u < 8; u++) {
    int a = lane * 8 + u;
    add[u] = bh2att2[a] + b_pvf[a];
    wal[u] = walpha2[a];
  }
#pragma unroll
  for (int z = 0; z < 4; z++) {
    const float* ap = atthp + (long)z * 524288 + (long)b * 1024 + 512 + lane * 8;
#pragma unroll
    for (int u = 0; u < 8; u++) add[u] += ap[u];
  }
  for (int j = wv; j < 36; j += 4) {
    half8 hv = *(const half8*)&pvf16[((long)b * 36 + j) * 512 + lane * 8];
    float acc = 0.f;
#pragma unroll
    for (int u = 0; u < 8; u++)
      acc += fast_tanh((float)hv[u] + add[u]) * wal[u];
#pragma unroll
    for (int off = 32; off; off >>= 1) acc += __shfl_xor(acc, off);
    if (lane == 0) w[j] = acc + balpha2[0];
  }
  __syncthreads();
  float mx = -3.0e38f;
  for (int i = 0; i < 36; i++) mx = fmaxf(mx, w[i]);
  float sum = 0.f;
  for (int i = 0; i < 36; i++) sum += __expf(w[i] - mx);
  float inv = 1.f / sum;
  __syncthreads();
  if (tid < 36) w[tid] = __expf(w[tid] - mx) * inv;
  __syncthreads();
  f32x4 acc = (f32x4){0.f, 0.f, 0.f, 0.f};
  const _Float16* fb = arr1h + (long)b * 36 * 1024 + tid * 4;
#pragma unroll 4
  for (int s = 0; s < 36; s++) {
    float ws = w[s];
    half4 v = *(const half4*)(fb + (long)s * 1024);
#pragma unroll
    for (int j = 0; j < 4; j++) acc[j] += ws * (float)v[j];
  }
  half4 h;
#pragma unroll
  for (int j = 0; j < 4; j++) h[j] = (_Float16)acc[j];
  *(half4*)&x2h[(long)b * 4096 + tid * 4] = h;
}

// ---------------------------------------------------------------------------
extern "C" void kernel_launch(void* const* d_in, const int* in_sizes, int n_in,
                              void* d_out, int out_size, void* d_ws, size_t ws_size,
                              hipStream_t stream) {
  const float* xt        = (const float*)d_in[0];
  const float* fc_feats  = (const float*)d_in[1];
  const float* att_feats = (const float*)d_in[2];
  const float* p_att     = (const float*)d_in[3];
  const float* state_h   = (const float*)d_in[4];
  const float* state_c   = (const float*)d_in[5];
  const float* b_ih_att  = (const float*)d_in[7];
  const float* b_hh_att  = (const float*)d_in[9];
  const float* b_ih_lang = (const float*)d_in[11];
  const float* b_hh_lang = (const float*)d_in[13];
  const float* bh2att1   = (const float*)d_in[15];
  const float* Walpha1   = (const float*)d_in[16];
  const float* balpha1   = (const float*)d_in[17];
  const float* bh2att2   = (const float*)d_in[19];
  const float* Walpha2   = (const float*)d_in[20];
  const float* balpha2   = (const float*)d_in[21];
  const float* b_vf      = (const float*)d_in[23];
  const float* b_pvf     = (const float*)d_in[25];

  float* out = (float*)d_out;
  float* W = (float*)d_ws;   // pool, f32-unit offsets; flat layout

  _Float16* WcAh   = (_Float16*)(W + 0);         // [4096][4096] fp16 hi
  _Float16* WcAl   = (_Float16*)(W + 8388608);   // [4096][4096] fp16 lo
  _Float16* WcLh   = (_Float16*)(W + 16777216);  // [4096][4096] fp16 (lang)
  _Float16* X1h    = (_Float16*)(W + 25165824);  // [512][4096]
  _Float16* X1l    = (_Float16*)(W + 26214400);  // [512][4096]
  float*    g1p    = W + 27262976;               // [4][512][4096] f32
  _Float16* hatt_h = (_Float16*)(W + 35651584);  // [512][1024]
  _Float16* W12h   = (_Float16*)(W + 35913728);  // [1024][1024]
  _Float16* Wvfh   = (_Float16*)(W + 36438016);  // [196][2048]
  _Float16* Wvfl   = (_Float16*)(W + 36638720);  // [196][2048]
  _Float16* Wpvfh  = (_Float16*)(W + 36839424);  // [512][1024]
  float*    atthp  = W + 37101568;               // [4][512][1024] f32
  _Float16* conch  = (_Float16*)(W + 39198720);  // [512][2048]
  _Float16* concl  = (_Float16*)(W + 39723008);  // [512][2048]
  _Float16* X2h    = (_Float16*)(W + 40247296);  // [512][4096]
  float*    vfhap  = W + 41396224;               // [16][512][196] f32
  _Float16* arr1h  = (_Float16*)(W + 43020288);  // [18432][1024]
  _Float16* pvf16  = (_Float16*)(W + 52457472);  // [18432][512]
  _Float16* g2ph   = (_Float16*)(W + 57176064);  // [4][512][4096] fp16

  float* out_h0 = out + 524288;
  float* out_h1 = out + 2 * 524288;
  float* out_c0 = out + 3 * 524288;
  float* out_c1 = out + 4 * 524288;

  // 1. prep: all weight converts + X1 hi/lo pack (one kernel)
  prep_kernel<<<36744, 256, 0, stream>>>(
      (const float*)d_in[6], (const float*)d_in[8],
      (const float*)d_in[10], (const float*)d_in[12],
      (const float*)d_in[14], (const float*)d_in[18],
      (const float*)d_in[22], (const float*)d_in[24],
      xt, fc_feats, state_h,
      WcAh, WcAl, WcLh, W12h, Wvfh, Wvfl, Wpvfh, X1h, X1l);

  // 2. att-LSTM gates: split-3, z=4 (512 blocks = 2/CU), counted-vmcnt pipeline
  gemm16<3, 0, 0, 0><<<dim3(32, 4, 4), 256, 0, stream>>>(
      X1h, X1l, 4096, WcAh, WcAl, 4096, g1p, 4096, 2097152, 4096, 1024);

  // 3. att-LSTM activation (sums 4 f32 partials; fills conc/X2h slots)
  lstm_act_kernel<4, false, true><<<2048, 256, 0, stream>>>(
      g1p, b_ih_att, b_hh_att, state_c, out_h0, out_c0,
      hatt_h, conch, concl, X2h, state_h, nullptr);

  // 4. fused atth1|atth2 projection, z=4 (partials consumed by att1/vfatt)
  gemm16<1, 0, 0, 0><<<dim3(8, 4, 4), 256, 0, stream>>>(
      hatt_h, nullptr, 1024, W12h, nullptr, 1024, atthp, 1024, 524288, 1024, 256);

  // 5. fused attention-1: scores + softmax + weighted sum
  att1_kernel<<<512, 256, 0, stream>>>(
      p_att, atthp, bh2att1, Walpha1, balpha1, att_feats, conch, concl, X2h);

  // 6. vf logits, split-3, z=16 (128 blocks; partials summed in topk)
  gemm16<3, 0, 1, 0><<<dim3(2, 4, 16), 256, 0, stream>>>(
      conch, concl, 2048, Wvfh, Wvfl, 2048, vfhap, 196, 100352, 196, 128);

  // 7. fused top-36 + gather + fp16 convert
  topk_gather_kernel<16><<<512, 256, 0, stream>>>(vfhap, b_vf, att_feats, arr1h);

  // 8. p_vf_feats (fp16 out); SWAPXY: same-M blocks stride 144 (=0 mod 8)
  gemm16<1, 1, 0, 1><<<dim3(144, 4, 1), 256, 0, stream>>>(
      arr1h, nullptr, 1024, Wpvfh, nullptr, 1024, pvf16, 512, 0, 512, 1024);

  // 9. attention-2 merged: scores + softmax + weighted sum -> X2h[:,0:1024]
  vfatt_kernel<<<512, 256, 0, stream>>>(
      pvf16, atthp, bh2att2, b_pvf, Walpha2, balpha2, arr1h, X2h);

  // 10. lang-LSTM gates: plain fp16, z=4, fp16 partials
  gemm16<1, 1, 0, 0><<<dim3(32, 4, 4), 256, 0, stream>>>(
      X2h, nullptr, 4096, WcLh, nullptr, 4096, g2ph, 4096, 2097152, 4096, 1024);

  // 11. lang-LSTM activation -> output (sums 4 fp16 partials)
  lstm_act_kernel<4, true, false><<<2048, 256, 0, stream>>>(
      g2ph, b_ih_lang, b_hh_lang, state_c + 524288, out, out_c1,
      nullptr, nullptr, nullptr, nullptr, nullptr, out_h1);
}